// Round 2
// baseline (704.951 us; speedup 1.0000x reference)
//
#include <hip/hip_runtime.h>

#define NB   32
#define NQL  2048
#define NKL  2048
#define DH   128
#define QBLK 64
#define KBLK 64
#define NT   (NKL / KBLK)
#define EPS  1e-6f

typedef __bf16 bf16x8 __attribute__((ext_vector_type(8)));
typedef __bf16 bf16x4 __attribute__((ext_vector_type(4)));
typedef float  f32x4  __attribute__((ext_vector_type(4)));

// One block = one (batch, 64-row Q tile). 4 waves; wave w owns q rows [w*16, w*16+16).
// Swapped QK^T: S^T = K·Q^T so lane's lq = q; softmax state is lane-local in k.
// Pipeline: regs hold tile kt's f32 K/V (loaded during tile kt-1's compute);
// staging phase converts+writes them; next tile's loads issue before compute.
__global__ __launch_bounds__(256, 3) void
attn_kernel(const float* __restrict__ Qg, const float* __restrict__ Kg,
            const float* __restrict__ Vg, const float* __restrict__ Mg,
            float* __restrict__ Og)
{
    // XCD swizzle: 1024 wgs, 8 XCDs -> each XCD gets 4 whole batches (K/V L2 reuse)
    const int wg = ((blockIdx.x & 7) << 7) | (blockIdx.x >> 3);
    const int b  = wg >> 5;
    const int q0 = (wg & 31) * QBLK;

    const int t  = threadIdx.x;
    const int w  = t >> 6;     // wave 0..3
    const int l  = t & 63;
    const int lq = l & 15;
    const int lg = l >> 4;

    // K row-major [k][d], V transposed [d][k]; both 16B-aligned rows with
    // XOR swizzle (col ^= (row&7)<<3 in shorts) -> uniform 8-slot bank spread.
    __shared__ __align__(16) unsigned short Ks[64 * 128];
    __shared__ __align__(16) unsigned short Vs[128 * 64];
    __shared__ __align__(16) unsigned short Ps[4][16][72];

    // staging ownership
    const int rK   = t >> 2;           // K row 0..63 (wave-contiguous 16-row strips)
    const int cK   = (t & 3) * 32;     // K col (d) base
    const int dV   = t >> 1;           // V d-row 0..127 (lane-consecutive within wave)
    const int khV  = t & 1;            // V k-half (0: k 0..31, 1: k 32..63)
    const int swzK = (rK & 7) << 3;
    const int swzV = (dV & 7) << 3;
    const int swzL = (lq & 7) << 3;    // read-side swizzle (row&7 == lq&7 for our rows)

    const int qrow = q0 + w * 16 + lq;

    // Q fragment (B-operand: lane holds Q[qrow][c*32 + lg*8 + j])
    bf16x8 qf[4];
    {
        const float* qb = Qg + ((size_t)b * NQL + qrow) * DH;
        #pragma unroll
        for (int c = 0; c < 4; ++c) {
            const float* p = qb + c * 32 + lg * 8;
            float4 x = *(const float4*)(p);
            float4 y = *(const float4*)(p + 4);
            qf[c] = (bf16x8){ (__bf16)x.x, (__bf16)x.y, (__bf16)x.z, (__bf16)x.w,
                              (__bf16)y.x, (__bf16)y.y, (__bf16)y.z, (__bf16)y.w };
        }
    }

    float m_run = -1e30f, z_part = 0.f, s_part = 0.f;
    f32x4 oacc[8];
    #pragma unroll
    for (int n = 0; n < 8; ++n) oacc[n] = (f32x4){0.f, 0.f, 0.f, 0.f};

    // prefetch registers (f32, converted at write time next tile)
    float4 kreg[8];
    float  vreg[32];
    float  mkf[16];

    const float* kbase = Kg + (size_t)b * NKL * DH;
    const float* vbase = Vg + (size_t)b * NKL * DH;
    const float* mbase = Mg + ((size_t)b * NQL + qrow) * NKL;

    auto load_kv = [&](int k0) {
        const float* kb = kbase + (size_t)(k0 + rK) * DH + cK;
        #pragma unroll
        for (int i = 0; i < 8; ++i) kreg[i] = *(const float4*)(kb + i * 4);
        // V columns: lane-consecutive dV -> each instr = 2 full 128B lines
        const float* vb = vbase + (size_t)(k0 + khV * 32) * DH + dV;
        #pragma unroll
        for (int kk = 0; kk < 32; ++kk) vreg[kk] = vb[kk * DH];
    };
    auto load_mask = [&](int k0) {
        const float* mb = mbase + k0;
        #pragma unroll
        for (int m = 0; m < 4; ++m) {
            float4 x = *(const float4*)(mb + m * 16 + lg * 4);
            mkf[m * 4 + 0] = x.x; mkf[m * 4 + 1] = x.y;
            mkf[m * 4 + 2] = x.z; mkf[m * 4 + 3] = x.w;
        }
    };

    load_kv(0);
    load_mask(0);

    const float scale = 0.08838834764831845f;   // 1/sqrt(128)

    for (int kt = 0; kt < NT; ++kt) {
        __syncthreads();   // all waves done reading LDS of tile kt-1

        // ---- staging: convert held regs -> bf16 LDS (short phase, no loads) ----
        #pragma unroll
        for (int i = 0; i < 4; ++i) {
            float4 a = kreg[2 * i], c = kreg[2 * i + 1];
            *(bf16x8*)&Ks[rK * 128 + ((cK + i * 8) ^ swzK)] =
                (bf16x8){ (__bf16)a.x, (__bf16)a.y, (__bf16)a.z, (__bf16)a.w,
                          (__bf16)c.x, (__bf16)c.y, (__bf16)c.z, (__bf16)c.w };
        }
        #pragma unroll
        for (int i = 0; i < 4; ++i) {
            *(bf16x8*)&Vs[dV * 64 + (((khV << 5) + i * 8) ^ swzV)] =
                (bf16x8){ (__bf16)vreg[i*8+0], (__bf16)vreg[i*8+1],
                          (__bf16)vreg[i*8+2], (__bf16)vreg[i*8+3],
                          (__bf16)vreg[i*8+4], (__bf16)vreg[i*8+5],
                          (__bf16)vreg[i*8+6], (__bf16)vreg[i*8+7] };
        }
        __syncthreads();

        // ---- issue next tile's K/V loads; latency hides under compute ----
        if (kt + 1 < NT) load_kv((kt + 1) * KBLK);

        // ---- S^T = K·Q^T ----
        f32x4 sacc[4];
        #pragma unroll
        for (int m = 0; m < 4; ++m) sacc[m] = (f32x4){0.f, 0.f, 0.f, 0.f};
        __builtin_amdgcn_s_setprio(1);
        #pragma unroll
        for (int m = 0; m < 4; ++m) {
            #pragma unroll
            for (int c = 0; c < 4; ++c) {
                bf16x8 af = *(bf16x8*)&Ks[(m * 16 + lq) * 128 + ((c * 32 + lg * 8) ^ swzL)];
                sacc[m] = __builtin_amdgcn_mfma_f32_16x16x32_bf16(af, qf[c], sacc[m], 0, 0, 0);
            }
        }
        __builtin_amdgcn_s_setprio(0);

        // ---- online softmax (lane owns 16 scores of q=qrow) ----
        float sv[4][4], tmax = -1e30f;
        #pragma unroll
        for (int m = 0; m < 4; ++m)
            #pragma unroll
            for (int r = 0; r < 4; ++r) {
                sv[m][r] = sacc[m][r] * scale;
                tmax = fmaxf(tmax, sv[m][r]);
            }
        tmax = fmaxf(tmax, __shfl_xor(tmax, 16));
        tmax = fmaxf(tmax, __shfl_xor(tmax, 32));
        const float mnew  = fmaxf(m_run, tmax);
        const float alpha = __expf(m_run - mnew);
        m_run = mnew;

        float zl = 0.f, sl = 0.f, pm[4][4];
        #pragma unroll
        for (int m = 0; m < 4; ++m)
            #pragma unroll
            for (int r = 0; r < 4; ++r) {
                float p  = __expf(sv[m][r] - mnew);
                zl += p;
                float pq = p * mkf[m * 4 + r];
                sl += pq;
                pm[m][r] = pq;
            }
        z_part = z_part * alpha + zl;
        s_part = s_part * alpha + sl;

        // P -> per-wave LDS (b64 writes; aligned-uniform banks on stride 72)
        #pragma unroll
        for (int m = 0; m < 4; ++m) {
            *(bf16x4*)&Ps[w][lq][m * 16 + lg * 4] =
                (bf16x4){ (__bf16)pm[m][0], (__bf16)pm[m][1],
                          (__bf16)pm[m][2], (__bf16)pm[m][3] };
        }

        // rescale O by alpha(q); O rows are q = lg*4 + r
        float alr[4];
        #pragma unroll
        for (int r = 0; r < 4; ++r) alr[r] = __shfl(alpha, lg * 4 + r);
        #pragma unroll
        for (int n = 0; n < 8; ++n)
            #pragma unroll
            for (int r = 0; r < 4; ++r) oacc[n][r] *= alr[r];

        // next tile's mask (consumed next softmax; long latency budget)
        if (kt + 1 < NT) load_mask((kt + 1) * KBLK);

        // ---- O += P·V ----
        __builtin_amdgcn_s_setprio(1);
        #pragma unroll
        for (int kc = 0; kc < 2; ++kc) {
            bf16x8 pa = *(bf16x8*)&Ps[w][lq][kc * 32 + lg * 8];
            #pragma unroll
            for (int n = 0; n < 8; ++n) {
                bf16x8 vv = *(bf16x8*)&Vs[(n * 16 + lq) * 64 + ((kc * 32 + lg * 8) ^ swzL)];
                oacc[n] = __builtin_amdgcn_mfma_f32_16x16x32_bf16(pa, vv, oacc[n], 0, 0, 0);
            }
        }
        __builtin_amdgcn_s_setprio(0);
    }

    // epilogue: finish cross-lane Z/S reduction, divide, store
    float z = z_part + __shfl_xor(z_part, 16);
    z += __shfl_xor(z, 32);
    float s = s_part + __shfl_xor(s_part, 16);
    s += __shfl_xor(s, 32);
    const float inv = 1.f / (s + EPS * z);
    float ivr[4];
    #pragma unroll
    for (int r = 0; r < 4; ++r) ivr[r] = __shfl(inv, lg * 4 + r);

    float* ob = Og + ((size_t)b * NQL + q0 + w * 16) * DH;
    #pragma unroll
    for (int n = 0; n < 8; ++n)
        #pragma unroll
        for (int r = 0; r < 4; ++r)
            ob[(size_t)(lg * 4 + r) * DH + n * 16 + lq] = oacc[n][r] * ivr[r];
}

extern "C" void kernel_launch(void* const* d_in, const int* in_sizes, int n_in,
                              void* d_out, int out_size, void* d_ws, size_t ws_size,
                              hipStream_t stream)
{
    const float* Q = (const float*)d_in[0];
    const float* K = (const float*)d_in[1];
    const float* V = (const float*)d_in[2];
    const float* M = (const float*)d_in[3];
    float* O = (float*)d_out;
    dim3 grid(NB * (NQL / QBLK));   // 1024
    attn_kernel<<<grid, 256, 0, stream>>>(Q, K, V, M, O);
}